// Round 4
// baseline (193.985 us; speedup 1.0000x reference)
//
#include <hip/hip_runtime.h>
#include <cstdint>

#define EMB 512
#define FFN 2048
#define NQ 8
#define M_TOTAL 32768

#define BM 256
#define BN 128
#define BK 64
#define NTHREADS 256    // 4 waves; wave tile 128m x 64n (wm = wave>>1, wn = wave&1)

typedef __attribute__((ext_vector_type(8))) short short8;   // 8 bf16 (MFMA A/B frag)
typedef __attribute__((ext_vector_type(4))) float float4v;  // MFMA C/D frag
typedef __attribute__((ext_vector_type(4))) unsigned int uint4v;

// fp32 -> bf16 bits, round-to-nearest-even (finite inputs)
static __device__ __forceinline__ unsigned int f2bf(float f) {
    unsigned int u = __builtin_bit_cast(unsigned int, f);
    return (u + 0x7fffu + ((u >> 16) & 1u)) >> 16;
}
static __device__ __forceinline__ unsigned int f2bf_pk(float lo, float hi) {
    return f2bf(lo) | (f2bf(hi) << 16);
}

// ---- generic fp32 -> packed bf16 converter (4 elems/thread) ----
__global__ __launch_bounds__(256) void conv_bf16(const float* __restrict__ src,
                                                 unsigned int* __restrict__ dst) {
    int idx = (blockIdx.x * 256 + threadIdx.x) * 4;
    float4 v = *(const float4*)&src[idx];
    dst[idx / 2]     = f2bf_pk(v.x, v.y);
    dst[idx / 2 + 1] = f2bf_pk(v.z, v.w);
}

// LDS tiles: row stride 64 bf16 = 128 B = 8 chunks of 16 B.
// Logical chunk c of row r stored at physical chunk c ^ (r & 7)  ->
// frag reads (16 rows x one chunk) land on all 32 banks per 8-lane phase.

__global__ __launch_bounds__(NTHREADS, 2) void ffq_main(
    const float* __restrict__ x,              // [M_TOTAL][EMB], cols 0..7 used
    const float* __restrict__ theta,          // [8]
    const unsigned short* __restrict__ w1b,   // [FFN][8] bf16 bits
    const unsigned short* __restrict__ w2b,   // [EMB][FFN] bf16 bits
    float* __restrict__ out)                  // [M_TOTAL][EMB]
{
    __shared__ unsigned short Asm[BM * BK];   // 32 KB h tile (swizzled)
    __shared__ unsigned short Bsm[BN * BK];   // 16 KB W2 tile (swizzled)

    const int t    = threadIdx.x;
    const int m0   = blockIdx.x * BM;
    const int n0   = blockIdx.y * BN;
    const int wave = t >> 6, lane = t & 63;
    const int quad = lane >> 4, l16 = lane & 15;
    const int wm   = wave >> 1, wn = wave & 1;

    // ---- per-wave persistent Q fragments: wave owns h-rows [wave*64, +64) ----
    // qfrag[mg]: lane l16 holds q[m0+wave*64+mg*16+l16][j=0..7] in quad 0;
    // quads 1..3 zero so the K=8..31 padding of the h-gen MFMA contributes 0.
    short8 qfrag[4];
#pragma unroll
    for (int mg = 0; mg < 4; ++mg) {
        int qrow = m0 + wave * 64 + mg * 16 + l16;
        const float* xr = x + (size_t)qrow * EMB;
        float4 xa = *(const float4*)xr;
        float4 xb = *(const float4*)(xr + 4);
        uint4v uq;
        uq[0] = f2bf_pk(__cosf(2.f * xa.x + theta[0]), __cosf(2.f * xa.y + theta[1]));
        uq[1] = f2bf_pk(__cosf(2.f * xa.z + theta[2]), __cosf(2.f * xa.w + theta[3]));
        uq[2] = f2bf_pk(__cosf(2.f * xb.x + theta[4]), __cosf(2.f * xb.y + theta[5]));
        uq[3] = f2bf_pk(__cosf(2.f * xb.z + theta[6]), __cosf(2.f * xb.w + theta[7]));
        qfrag[mg] = __builtin_bit_cast(short8, uq);
        if (quad != 0) qfrag[mg] = (short8)0;
    }

    // ---- W1 fragment prefetch (bf16, global; 512 B/iter, L1/L2-hot) ----
    short8 wA[4];
#pragma unroll
    for (int fg = 0; fg < 4; ++fg)
        wA[fg] = *(const short8*)&w1b[(size_t)(fg * 16 + l16) * NQ];

    float4v acc[32];
#pragma unroll
    for (int i = 0; i < 32; ++i) acc[i] = (float4v)0.0f;

    for (int k0 = 0; k0 < FFN; k0 += BK) {                 // 32 iterations
        __syncthreads();   // previous iter's tiles fully consumed

        // ---- async stage B tile [BN][BK] = 16 KB = 1024 x 16 B chunks ----
#pragma unroll
        for (int i = 0; i < 4; ++i) {
            int c = i * NTHREADS + t;          // physical chunk; per-wave lane-contiguous dest
            int n = c >> 3, s = c & 7;
            int qk = s ^ (n & 7);              // source-swizzle the global k-chunk
            const unsigned short* g = w2b + (size_t)(n0 + n) * FFN + k0 + qk * 8;
            __builtin_amdgcn_global_load_lds(
                (const __attribute__((address_space(1))) unsigned int*)g,
                (__attribute__((address_space(3))) unsigned int*)(uintptr_t)(Bsm + c * 8),
                16, 0, 0);
        }

        // ---- consume prefetched W1 frags; issue next iter's prefetch ----
        short8 w1f[4];
#pragma unroll
        for (int fg = 0; fg < 4; ++fg) w1f[fg] = wA[fg];
        int kn = (k0 + BK < FFN) ? (k0 + BK) : 0;
#pragma unroll
        for (int fg = 0; fg < 4; ++fg)
            wA[fg] = *(const short8*)&w1b[(size_t)(kn + fg * 16 + l16) * NQ];

        // ---- h-gen via MFMA: H[f][m] = sum_j W1[f][j]*q[m][j], relu, ->Asm ----
        // A = w1f (lane l16 -> f row), B = qfrag. D: row=quad*4+r -> f_local,
        // col=l16 -> m. Lane holds 4 consecutive f for one m -> one b64 store.
        const int mbase = wave * 64;
#pragma unroll
        for (int mg = 0; mg < 4; ++mg) {
            int mloc = mbase + mg * 16 + l16;
            unsigned int rowoff = mloc * BK;
#pragma unroll
            for (int fg = 0; fg < 4; ++fg) {
                float4v hc = __builtin_amdgcn_mfma_f32_16x16x32_bf16(
                    w1f[fg], qfrag[mg], (float4v)0.0f, 0, 0, 0);
                unsigned int p0 = f2bf_pk(fmaxf(hc[0], 0.f), fmaxf(hc[1], 0.f));
                unsigned int p1 = f2bf_pk(fmaxf(hc[2], 0.f), fmaxf(hc[3], 0.f));
                int c    = fg * 2 + (quad >> 1);       // logical chunk of these 4 f
                int phys = c ^ (l16 & 7);              // row&7 == l16&7
                unsigned long long pk = ((unsigned long long)p1 << 32) | p0;
                *(unsigned long long*)&Asm[rowoff + phys * 8 + (quad & 1) * 4] = pk;
            }
        }

        __syncthreads();   // Asm written + Bsm DMA drained

        // ---- main MFMA: two K=32 halves; af in groups of 4 to cap VGPRs ----
#pragma unroll
        for (int h = 0; h < 2; ++h) {
            const int pk8 = (((h * 4 + quad) ^ (l16 & 7)) * 8);
            short8 bfv[4];
#pragma unroll
            for (int fn = 0; fn < 4; ++fn)
                bfv[fn] = *(const short8*)&Bsm[(wn * 64 + fn * 16 + l16) * BK + pk8];
#pragma unroll
            for (int half = 0; half < 2; ++half) {
                short8 af[4];
#pragma unroll
                for (int i = 0; i < 4; ++i) {
                    int fm = half * 4 + i;
                    af[i] = *(const short8*)&Asm[(wm * 128 + fm * 16 + l16) * BK + pk8];
                }
#pragma unroll
                for (int i = 0; i < 4; ++i)
#pragma unroll
                    for (int fn = 0; fn < 4; ++fn)
                        acc[(half * 4 + i) * 4 + fn] = __builtin_amdgcn_mfma_f32_16x16x32_bf16(
                            af[i], bfv[fn], acc[(half * 4 + i) * 4 + fn], 0, 0, 0);
            }
        }
    }

    // ---- epilogue: D layout col=l16 (n), row=quad*4+r (m) ----
    const int om = m0 + wm * 128;
    const int on = n0 + wn * 64;
#pragma unroll
    for (int fm = 0; fm < 8; ++fm) {
#pragma unroll
        for (int fn = 0; fn < 4; ++fn) {
            float4v v = acc[fm * 4 + fn];
            int rbase = om + fm * 16 + quad * 4;
            int c     = on + fn * 16 + l16;
#pragma unroll
            for (int r = 0; r < 4; ++r)
                out[(size_t)(rbase + r) * EMB + c] = v[r];
        }
    }
}

extern "C" void kernel_launch(void* const* d_in, const int* in_sizes, int n_in,
                              void* d_out, int out_size, void* d_ws, size_t ws_size,
                              hipStream_t stream) {
    const float* x     = (const float*)d_in[0];
    const float* theta = (const float*)d_in[1];
    const float* W1    = (const float*)d_in[2];
    const float* W2    = (const float*)d_in[3];
    float* out = (float*)d_out;

    unsigned int* w2b = (unsigned int*)d_ws;                       // 2 MiB
    unsigned int* w1b = (unsigned int*)((char*)d_ws + (size_t)EMB * FFN * 2);  // 32 KiB

    conv_bf16<<<(EMB * FFN) / (256 * 4), 256, 0, stream>>>(W2, w2b);
    conv_bf16<<<(FFN * NQ) / (256 * 4), 256, 0, stream>>>(W1, w1b);

    dim3 grid(M_TOTAL / BM, EMB / BN);     // 128 x 4 = 512 blocks, 2/CU
    ffq_main<<<grid, NTHREADS, 0, stream>>>(x, theta,
        (const unsigned short*)w1b, (const unsigned short*)w2b, out);
}

// Round 5
// 179.605 us; speedup vs baseline: 1.0801x; 1.0801x over previous
//
#include <hip/hip_runtime.h>
#include <cstdint>

#define EMB 512
#define FFN 2048
#define NQ 8
#define M_TOTAL 32768

#define BM 128
#define BN 256
#define BK 32
#define NTHREADS 512    // 8 waves: wm = wave>>2 (2), wn = wave&3 (4); wave tile 64x64

#define ASZ (BM * BK)   // one A buffer (shorts)
#define BSZ (BN * BK)   // one B buffer (shorts)

typedef __attribute__((ext_vector_type(8))) short short8;   // 8 bf16 (MFMA A/B frag)
typedef __attribute__((ext_vector_type(4))) float float4v;  // MFMA C/D frag
typedef __attribute__((ext_vector_type(4))) unsigned int uint4v;

// fp32 -> bf16 bits, round-to-nearest-even (finite inputs)
static __device__ __forceinline__ unsigned int f2bf(float f) {
    unsigned int u = __builtin_bit_cast(unsigned int, f);
    return (u + 0x7fffu + ((u >> 16) & 1u)) >> 16;
}
static __device__ __forceinline__ unsigned int f2bf_pk(float lo, float hi) {
    return f2bf(lo) | (f2bf(hi) << 16);
}

// ---- generic fp32 -> packed bf16 converter (4 elems/thread) ----
__global__ __launch_bounds__(256) void conv_bf16(const float* __restrict__ src,
                                                 unsigned int* __restrict__ dst) {
    int idx = (blockIdx.x * 256 + threadIdx.x) * 4;
    float4 v = *(const float4*)&src[idx];
    dst[idx / 2]     = f2bf_pk(v.x, v.y);
    dst[idx / 2 + 1] = f2bf_pk(v.z, v.w);
}

// LDS tiles: row stride 32 bf16 = 64 B = 4 chunks of 16 B.
// Logical chunk q of row r stored at physical chunk q ^ ((r>>1)&3) ->
// fragment reads (16 rows x one chunk each) cover all 32 banks per 8-lane phase.

__global__ __launch_bounds__(NTHREADS, 4) void ffq_main(
    const float* __restrict__ x,              // [M_TOTAL][EMB], cols 0..7 used
    const float* __restrict__ theta,          // [8]
    const unsigned short* __restrict__ w1b,   // [FFN][8] bf16 bits
    const unsigned short* __restrict__ w2b,   // [EMB][FFN] bf16 bits
    float* __restrict__ out)                  // [M_TOTAL][EMB]
{
    __shared__ unsigned short Asm[2 * ASZ];   // 16 KB h tile, ping-pong, swizzled
    __shared__ unsigned short Bsm[2 * BSZ];   // 32 KB W2 tile, ping-pong, swizzled

    const int t    = threadIdx.x;
    const int m0   = blockIdx.x * BM;
    const int n0   = blockIdx.y * BN;
    const int wave = t >> 6, lane = t & 63;
    const int quad = lane >> 4, l16 = lane & 15;
    const int wm   = wave >> 2, wn = wave & 3;

    // ---- per-wave persistent Q fragment: wave owns h-rows [wave*16, +16) ----
    // lane l16 holds q[m0+wave*16+l16][j=0..7] in quad 0 (K slots 0..7);
    // quads 1..3 zero so the K=8..31 padding of the h-gen MFMA contributes 0.
    short8 qfrag;
    {
        int qrow = m0 + wave * 16 + l16;
        const float* xr = x + (size_t)qrow * EMB;
        float4 xa = *(const float4*)xr;
        float4 xb = *(const float4*)(xr + 4);
        uint4v uq;
        uq[0] = f2bf_pk(__cosf(2.f * xa.x + theta[0]), __cosf(2.f * xa.y + theta[1]));
        uq[1] = f2bf_pk(__cosf(2.f * xa.z + theta[2]), __cosf(2.f * xa.w + theta[3]));
        uq[2] = f2bf_pk(__cosf(2.f * xb.x + theta[4]), __cosf(2.f * xb.y + theta[5]));
        uq[3] = f2bf_pk(__cosf(2.f * xb.z + theta[6]), __cosf(2.f * xb.w + theta[7]));
        qfrag = __builtin_bit_cast(short8, uq);
        if (quad != 0) qfrag = (short8)0;
    }

    const int mrow   = wave * 16 + l16;             // h-gen output row (m, local)
    const int aswz   = (l16 >> 1) & 3;              // A-tile swizzle key for this row
    const int awoff  = mrow * BK + (quad & 1) * 4;  // A write base (chunk added later)

    // ================= prologue: produce tiles for k0 = 0 into buf 0 ========
#pragma unroll
    for (int i = 0; i < 2; ++i) {                   // DMA B(0)
        int c = i * NTHREADS + t;
        int n = c >> 2, s = c & 3;
        int qk = s ^ ((n >> 1) & 3);
        const unsigned short* g = w2b + (size_t)(n0 + n) * FFN + qk * 8;
        __builtin_amdgcn_global_load_lds(
            (const __attribute__((address_space(1))) unsigned int*)g,
            (__attribute__((address_space(3))) unsigned int*)(uintptr_t)(Bsm + c * 8),
            16, 0, 0);
    }
#pragma unroll
    for (int fh = 0; fh < 2; ++fh) {                // h-gen(0)
        int f = fh * 16 + l16;
        short8 w1f = *(const short8*)&w1b[(size_t)f * NQ];
        float4v hc = __builtin_amdgcn_mfma_f32_16x16x32_bf16(
            w1f, qfrag, (float4v)0.0f, 0, 0, 0);
        unsigned int p0 = f2bf_pk(fmaxf(hc[0], 0.f), fmaxf(hc[1], 0.f));
        unsigned int p1 = f2bf_pk(fmaxf(hc[2], 0.f), fmaxf(hc[3], 0.f));
        int qph = (fh * 2 + (quad >> 1)) ^ aswz;
        unsigned long long pk = ((unsigned long long)p1 << 32) | p0;
        *(unsigned long long*)&Asm[awoff + qph * 8] = pk;
    }

    float4v acc[16];
#pragma unroll
    for (int i = 0; i < 16; ++i) acc[i] = (float4v)0.0f;

    // ================= main loop: ONE barrier per iteration =================
    for (int k0 = 0; k0 < FFN; k0 += BK) {          // 64 iterations
        const int bb = (k0 >> 5) & 1;
        const int nb = bb ^ 1;
        __syncthreads();   // buf bb ready (DMA drained, h written); buf nb free

        const int kn = k0 + BK;
        if (kn < FFN) {
            // ---- produce B(kn) via DMA into buf nb ----
#pragma unroll
            for (int i = 0; i < 2; ++i) {
                int c = i * NTHREADS + t;
                int n = c >> 2, s = c & 3;
                int qk = s ^ ((n >> 1) & 3);
                const unsigned short* g = w2b + (size_t)(n0 + n) * FFN + kn + qk * 8;
                __builtin_amdgcn_global_load_lds(
                    (const __attribute__((address_space(1))) unsigned int*)g,
                    (__attribute__((address_space(3))) unsigned int*)(uintptr_t)(Bsm + nb * BSZ + c * 8),
                    16, 0, 0);
            }
            // ---- produce h(kn) into buf nb (full iter of slack; W1 from L1) ----
#pragma unroll
            for (int fh = 0; fh < 2; ++fh) {
                int f = kn + fh * 16 + l16;
                short8 w1f = *(const short8*)&w1b[(size_t)f * NQ];
                float4v hc = __builtin_amdgcn_mfma_f32_16x16x32_bf16(
                    w1f, qfrag, (float4v)0.0f, 0, 0, 0);
                unsigned int p0 = f2bf_pk(fmaxf(hc[0], 0.f), fmaxf(hc[1], 0.f));
                unsigned int p1 = f2bf_pk(fmaxf(hc[2], 0.f), fmaxf(hc[3], 0.f));
                int qph = (fh * 2 + (quad >> 1)) ^ aswz;
                unsigned long long pk = ((unsigned long long)p1 << 32) | p0;
                *(unsigned long long*)&Asm[nb * ASZ + awoff + qph * 8] = pk;
            }
        }

        // ---- consume buf bb: conflict-free fragment reads + 16 MFMA ----
        short8 af[4], bfr[4];
#pragma unroll
        for (int fm = 0; fm < 4; ++fm) {
            int row = wm * 64 + fm * 16 + l16;
            int qph = quad ^ ((row >> 1) & 3);
            af[fm] = *(const short8*)&Asm[bb * ASZ + row * BK + qph * 8];
        }
#pragma unroll
        for (int fn = 0; fn < 4; ++fn) {
            int row = wn * 64 + fn * 16 + l16;
            int qph = quad ^ ((row >> 1) & 3);
            bfr[fn] = *(const short8*)&Bsm[bb * BSZ + row * BK + qph * 8];
        }
#pragma unroll
        for (int fm = 0; fm < 4; ++fm)
#pragma unroll
            for (int fn = 0; fn < 4; ++fn)
                acc[fm * 4 + fn] = __builtin_amdgcn_mfma_f32_16x16x32_bf16(
                    af[fm], bfr[fn], acc[fm * 4 + fn], 0, 0, 0);
    }

    // ---- epilogue: D layout col=l16 (n), row=quad*4+r (m) ----
    const int om = m0 + wm * 64;
    const int on = n0 + wn * 64;
#pragma unroll
    for (int fm = 0; fm < 4; ++fm) {
#pragma unroll
        for (int fn = 0; fn < 4; ++fn) {
            float4v v = acc[fm * 4 + fn];
            int rbase = om + fm * 16 + quad * 4;
            int c     = on + fn * 16 + l16;
#pragma unroll
            for (int r = 0; r < 4; ++r)
                out[(size_t)(rbase + r) * EMB + c] = v[r];
        }
    }
}

extern "C" void kernel_launch(void* const* d_in, const int* in_sizes, int n_in,
                              void* d_out, int out_size, void* d_ws, size_t ws_size,
                              hipStream_t stream) {
    const float* x     = (const float*)d_in[0];
    const float* theta = (const float*)d_in[1];
    const float* W1    = (const float*)d_in[2];
    const float* W2    = (const float*)d_in[3];
    float* out = (float*)d_out;

    unsigned int* w2b = (unsigned int*)d_ws;                                   // 2 MiB
    unsigned int* w1b = (unsigned int*)((char*)d_ws + (size_t)EMB * FFN * 2);  // 32 KiB

    conv_bf16<<<(EMB * FFN) / (256 * 4), 256, 0, stream>>>(W2, w2b);
    conv_bf16<<<(FFN * NQ) / (256 * 4), 256, 0, stream>>>(W1, w1b);

    dim3 grid(M_TOTAL / BM, EMB / BN);     // 256 x 2 = 512 blocks, 2/CU
    ffq_main<<<grid, NTHREADS, 0, stream>>>(x, theta,
        (const unsigned short*)w1b, (const unsigned short*)w2b, out);
}